// Round 3
// baseline (694.536 us; speedup 1.0000x reference)
//
#include <hip/hip_runtime.h>
#include <hip/hip_bf16.h>
#include <cstdint>
#include <cstddef>

// ---------------------------------------------------------------------------
// EnhancedMultiHeadAttention on MI355X (gfx950).
// EXTERNAL dtype: fp32 (per reference — round-2 NaN traced to reading fp32
// inputs as bf16: garbage low-half exponents -> inf/NaN in MFMA).
// INTERNAL dtype: bf16 (MFMA), fp32 softmax stats.
// Pipeline:
//   mix_kernel   : softmax(head_mixing fp32) -> MIXW fp32[16][16]
//   gemm<f32in>  : Q/K/V projections; A fp32->bf16 staged, W fp32 transposed
//                  into LDS in-kernel (no weight-transpose buffers), out bf16.
//                  Q pre-scaled by 1/8 (after bias, like ref).
//   transpose_v  : Vp[b,s,g*64+d] -> Vt[b,g,d,s]   (bf16)
//   pass1        : Z[b,h,q] = m + log l   (flash stats, MFMA QK^T)
//   pass2        : p=exp(s-Z) (Z folded into MFMA C-init), head-mix (VALU),
//                  PV (MFMA) -> CTX bf16 (aliases Vp)
//   gemm<f32out> : CTX @ Wo + bo -> d_out fp32
// ws ~34 MB: Zb/MIX + Qp + Kp + Vp(->CTX) + Vtt.
// MFMA 16x16x32 bf16 layouts (m89/m91/m120-verified):
//   A: m=lane&15, k=(lane>>4)*8+j ; B: n=lane&15, k=(lane>>4)*8+j
//   C/D: col=lane&15, row=(lane>>4)*4+reg
// ---------------------------------------------------------------------------

typedef __bf16 bf16_t;
typedef __bf16 bf16x8 __attribute__((ext_vector_type(8)));
typedef float f32x4 __attribute__((ext_vector_type(4)));

#define B_ 2
#define S_ 2048
#define E_ 1024
#define H_ 16
#define D_ 64

static __device__ __forceinline__ f32x4 mfma16(bf16x8 a, bf16x8 b, f32x4 c) {
  return __builtin_amdgcn_mfma_f32_16x16x32_bf16(a, b, c, 0, 0, 0);
}

// ---------------- mix = softmax(head_mixing, axis=-1), fp32 ----------------
__global__ void mix_kernel(const float* __restrict__ hm, float* __restrict__ mixw) {
  int g = threadIdx.x;
  if (g < H_) {
    float v[H_]; float mx = -1e30f;
    for (int h = 0; h < H_; h++) { v[h] = hm[g * H_ + h]; mx = fmaxf(mx, v[h]); }
    float s = 0.f;
    for (int h = 0; h < H_; h++) { v[h] = __expf(v[h] - mx); s += v[h]; }
    float inv = 1.f / s;
    for (int h = 0; h < H_; h++) mixw[g * H_ + h] = v[h] * inv;
  }
}

// ---------------- V transpose: Vp[b,s,g*64+d] -> Vt[(b*16+g)*64+d][s] ------
__global__ void transpose_v_kernel(const bf16_t* __restrict__ Vp, bf16_t* __restrict__ Vt) {
  __shared__ bf16_t t[32][33];
  const int tx = threadIdx.x & 31, ty = threadIdx.x >> 5;
  const int z = blockIdx.z, b = z >> 4, g = z & 15;
  const int s0 = blockIdx.x * 32, d0 = blockIdx.y * 32;
  const bf16_t* src = Vp + (size_t)b * S_ * E_ + g * 64;
  bf16_t* dst = Vt + (size_t)z * 64 * S_;
#pragma unroll
  for (int i = 0; i < 4; i++)
    t[ty + i * 8][tx] = src[(size_t)(s0 + ty + i * 8) * E_ + d0 + tx];
  __syncthreads();
#pragma unroll
  for (int i = 0; i < 4; i++)
    dst[(size_t)(d0 + ty + i * 8) * S_ + s0 + tx] = t[tx][ty + i * 8];
}

// ---------------- GEMM: C[4096,1024] = (A @ W + bias) * scale --------------
// W is fp32 [K][N] (reference layout) — transposed-converted into LDS here.
// AF32: A is fp32 (external input) else bf16. OF32: C is fp32 else bf16.
struct GemmSec {
  const void* A; const float* bias; const float* W; void* C; float scale;
};

template <bool AF32, bool OF32>
__global__ __launch_bounds__(256) void gemm_kernel(GemmSec s0, GemmSec s1, GemmSec s2) {
  const int z = blockIdx.z;
  GemmSec p = (z == 0) ? s0 : ((z == 1) ? s1 : s2);
  const int tid = threadIdx.x;
  const int wave = tid >> 6, lane = tid & 63;
  const int ln = lane & 15, qd = lane >> 4;
  const int wm = wave >> 1, wn = wave & 1;
  const int row0 = blockIdx.y * 128, col0 = blockIdx.x * 128;

  __shared__ __align__(16) bf16_t As[128 * 32];  // [row 128][k 32]
  __shared__ __align__(16) bf16_t Bs[128 * 32];  // [n 128][k 32]

  f32x4 z4 = {0.f, 0.f, 0.f, 0.f};
  f32x4 acc[4][4];
#pragma unroll
  for (int i = 0; i < 4; i++)
#pragma unroll
    for (int j = 0; j < 4; j++) acc[i][j] = z4;

  for (int ks = 0; ks < E_ / 32; ks++) {
    const int kk = ks * 32;
    // ---- A staging: 512 chunks of 8 elems; chunk c: row=c>>2, k=(c&3)*8
#pragma unroll
    for (int cc = 0; cc < 2; cc++) {
      const int c = tid + cc * 256;
      const int r = c >> 2, kc = (c & 3) * 8;
      if (AF32) {
        const float* Af = (const float*)p.A;
        f32x4 f0 = *(const f32x4*)&Af[(size_t)(row0 + r) * E_ + kk + kc];
        f32x4 f1 = *(const f32x4*)&Af[(size_t)(row0 + r) * E_ + kk + kc + 4];
        bf16x8 v;
#pragma unroll
        for (int j = 0; j < 4; j++) { v[j] = (bf16_t)f0[j]; v[4 + j] = (bf16_t)f1[j]; }
        *(bf16x8*)&As[r * 32 + kc] = v;
      } else {
        const bf16_t* Ab = (const bf16_t*)p.A;
        *(uint4*)&As[r * 32 + kc] = *(const uint4*)&Ab[(size_t)(row0 + r) * E_ + kk + kc];
      }
    }
    // ---- B staging with transpose: chunk c: krow=c&31, n=(c>>5)*8
#pragma unroll
    for (int cc = 0; cc < 2; cc++) {
      const int c = tid + cc * 256;
      const int kr = c & 31, nc = (c >> 5) * 8;
      f32x4 g0 = *(const f32x4*)&p.W[(size_t)(kk + kr) * E_ + col0 + nc];
      f32x4 g1 = *(const f32x4*)&p.W[(size_t)(kk + kr) * E_ + col0 + nc + 4];
#pragma unroll
      for (int j = 0; j < 4; j++) {
        Bs[(nc + j) * 32 + kr]     = (bf16_t)g0[j];
        Bs[(nc + 4 + j) * 32 + kr] = (bf16_t)g1[j];
      }
    }
    __syncthreads();
    bf16x8 af[4], bfr[4];
#pragma unroll
    for (int mt = 0; mt < 4; mt++) af[mt] = *(const bf16x8*)&As[(wm * 64 + mt * 16 + ln) * 32 + qd * 8];
#pragma unroll
    for (int nt = 0; nt < 4; nt++) bfr[nt] = *(const bf16x8*)&Bs[(wn * 64 + nt * 16 + ln) * 32 + qd * 8];
#pragma unroll
    for (int mt = 0; mt < 4; mt++)
#pragma unroll
      for (int nt = 0; nt < 4; nt++)
        acc[mt][nt] = mfma16(af[mt], bfr[nt], acc[mt][nt]);
    __syncthreads();
  }
  // ---- epilogue: (acc + bias) * scale (ref order: bias add, then /8 for Q)
#pragma unroll
  for (int nt = 0; nt < 4; nt++) {
    int col = col0 + wn * 64 + nt * 16 + ln;
    float bias_v = p.bias[col];
#pragma unroll
    for (int mt = 0; mt < 4; mt++) {
      int row = row0 + wm * 64 + mt * 16 + qd * 4;
#pragma unroll
      for (int r = 0; r < 4; r++) {
        float v = (acc[mt][nt][r] + bias_v) * p.scale;
        if (OF32) ((float*)p.C)[(size_t)(row + r) * E_ + col] = v;
        else      ((bf16_t*)p.C)[(size_t)(row + r) * E_ + col] = (bf16_t)v;
      }
    }
  }
}

// ---------------- pass 1: softmax stats Z = m + log(l) ---------------------
__global__ __launch_bounds__(256) void pass1_kernel(const bf16_t* __restrict__ Qp,
                                                    const bf16_t* __restrict__ Kp,
                                                    float* __restrict__ Z) {
  const int qc = blockIdx.x;
  const int bh = blockIdx.y;
  const int b = bh >> 4, h = bh & 15;
  const int tid = threadIdx.x;
  const int wave = tid >> 6, lane = tid & 63;
  const int ln = lane & 15, qd = lane >> 4;
  const size_t rowbase = (size_t)b * S_;
  const int qbase = qc * 256 + wave * 64;

  bf16x8 qf[4][2];
#pragma unroll
  for (int qs = 0; qs < 4; qs++)
#pragma unroll
    for (int db = 0; db < 2; db++)
      qf[qs][db] = *(const bf16x8*)&Qp[(rowbase + qbase + qs * 16 + ln) * E_ + h * 64 + db * 32 + qd * 8];

  float m[4][4], l[4][4];
#pragma unroll
  for (int qs = 0; qs < 4; qs++)
#pragma unroll
    for (int r = 0; r < 4; r++) { m[qs][r] = -1e30f; l[qs][r] = 0.f; }

  for (int kt = 0; kt < S_ / 64; kt++) {
    bf16x8 kf[4][2];
#pragma unroll
    for (int nt = 0; nt < 4; nt++)
#pragma unroll
      for (int db = 0; db < 2; db++)
        kf[nt][db] = *(const bf16x8*)&Kp[(rowbase + kt * 64 + nt * 16 + ln) * E_ + h * 64 + db * 32 + qd * 8];
#pragma unroll
    for (int qs = 0; qs < 4; qs++) {
      f32x4 sc[4];
#pragma unroll
      for (int nt = 0; nt < 4; nt++) {
        f32x4 c0 = {0.f, 0.f, 0.f, 0.f};
        c0 = mfma16(qf[qs][0], kf[nt][0], c0);
        sc[nt] = mfma16(qf[qs][1], kf[nt][1], c0);
      }
#pragma unroll
      for (int r = 0; r < 4; r++) {
        float tmax = fmaxf(fmaxf(sc[0][r], sc[1][r]), fmaxf(sc[2][r], sc[3][r]));
        float mn = fmaxf(m[qs][r], tmax);
        float add = __expf(sc[0][r] - mn) + __expf(sc[1][r] - mn) +
                    __expf(sc[2][r] - mn) + __expf(sc[3][r] - mn);
        l[qs][r] = l[qs][r] * __expf(m[qs][r] - mn) + add;
        m[qs][r] = mn;
      }
    }
  }
#pragma unroll
  for (int qs = 0; qs < 4; qs++) {
#pragma unroll
    for (int r = 0; r < 4; r++) {
      float mm = m[qs][r], ll = l[qs][r];
      for (int mask = 1; mask < 16; mask <<= 1) {
        float mo = __shfl_xor(mm, mask);
        float lo = __shfl_xor(ll, mask);
        float mn = fmaxf(mm, mo);
        ll = ll * __expf(mm - mn) + lo * __expf(mo - mn);
        mm = mn;
      }
      if (ln == 0) {
        int q = qbase + qs * 16 + qd * 4 + r;
        Z[(size_t)bh * S_ + q] = mm + __logf(ll);
      }
    }
  }
}

// ---------------- pass 2: p=exp(s-Z), head-mix, PV -> ctx bf16 -------------
__global__ __launch_bounds__(256) void pass2_kernel(const bf16_t* __restrict__ Qp,
                                                    const bf16_t* __restrict__ Kp,
                                                    const bf16_t* __restrict__ Vt,
                                                    const float* __restrict__ Z,
                                                    const float* __restrict__ mixw,
                                                    bf16_t* __restrict__ ctx) {
  const int id = blockIdx.x;            // 0..255
  const int b = id >> 7;
  const int qt = id & 127;
  const int q0 = qt * 16;

  const int tid = threadIdx.x;
  const int wave = tid >> 6, lane = tid & 63;
  const int ln = lane & 15, qd = lane >> 4;
  const int h0 = wave * 4;

  __shared__ __align__(16) bf16_t Plds[16 * 16 * 32];  // [h][q16][k32]
  __shared__ float mixLds[256];
  mixLds[tid] = mixw[tid];

  const size_t rowbase = (size_t)b * S_;

  bf16x8 qf[4][2];
#pragma unroll
  for (int hh = 0; hh < 4; hh++)
#pragma unroll
    for (int db = 0; db < 2; db++)
      qf[hh][db] = *(const bf16x8*)&Qp[(rowbase + q0 + ln) * E_ + (h0 + hh) * 64 + db * 32 + qd * 8];

  float Zr[4][4];
#pragma unroll
  for (int hh = 0; hh < 4; hh++)
#pragma unroll
    for (int r = 0; r < 4; r++)
      Zr[hh][r] = Z[((size_t)(b * H_ + h0 + hh)) * S_ + q0 + qd * 4 + r];

  f32x4 z4 = {0.f, 0.f, 0.f, 0.f};
  f32x4 cacc[4][4];
#pragma unroll
  for (int g = 0; g < 4; g++)
#pragma unroll
    for (int nt = 0; nt < 4; nt++) cacc[g][nt] = z4;

  for (int ks = 0; ks < S_ / 32; ks++) {
    const int kb = ks * 32;
#pragma unroll
    for (int hh = 0; hh < 4; hh++) {
      bf16x8 kf[2][2];
#pragma unroll
      for (int n2 = 0; n2 < 2; n2++)
#pragma unroll
        for (int db = 0; db < 2; db++)
          kf[n2][db] = *(const bf16x8*)&Kp[(rowbase + kb + n2 * 16 + ln) * E_ + (h0 + hh) * 64 + db * 32 + qd * 8];
#pragma unroll
      for (int n2 = 0; n2 < 2; n2++) {
        f32x4 c0;
        c0[0] = -Zr[hh][0]; c0[1] = -Zr[hh][1]; c0[2] = -Zr[hh][2]; c0[3] = -Zr[hh][3];
        c0 = mfma16(qf[hh][0], kf[n2][0], c0);
        c0 = mfma16(qf[hh][1], kf[n2][1], c0);
#pragma unroll
        for (int r = 0; r < 4; r++)
          Plds[((h0 + hh) * 16 + qd * 4 + r) * 32 + n2 * 16 + ln] = (bf16_t)__expf(c0[r]);
      }
    }
    __syncthreads();
    float ma[4][8];
#pragma unroll
    for (int g = 0; g < 4; g++)
#pragma unroll
      for (int j = 0; j < 8; j++) ma[g][j] = 0.f;
#pragma unroll
    for (int h = 0; h < H_; h++) {
      bf16x8 pf = *(const bf16x8*)&Plds[(h * 16 + ln) * 32 + qd * 8];
      float pv[8];
#pragma unroll
      for (int j = 0; j < 8; j++) pv[j] = (float)pf[j];
#pragma unroll
      for (int g = 0; g < 4; g++) {
        float wgt = mixLds[(h0 + g) * 16 + h];
#pragma unroll
        for (int j = 0; j < 8; j++) ma[g][j] += wgt * pv[j];
      }
    }
#pragma unroll
    for (int g = 0; g < 4; g++) {
      bf16x8 af;
#pragma unroll
      for (int j = 0; j < 8; j++) af[j] = (bf16_t)ma[g][j];
#pragma unroll
      for (int nt = 0; nt < 4; nt++) {
        bf16x8 vf = *(const bf16x8*)&Vt[((size_t)((b * H_ + h0 + g) * 64 + nt * 16 + ln)) * S_ + kb + qd * 8];
        cacc[g][nt] = mfma16(af, vf, cacc[g][nt]);
      }
    }
    __syncthreads();
  }
#pragma unroll
  for (int g = 0; g < 4; g++)
#pragma unroll
    for (int nt = 0; nt < 4; nt++)
#pragma unroll
      for (int r = 0; r < 4; r++)
        ctx[(rowbase + q0 + qd * 4 + r) * E_ + (h0 + g) * 64 + nt * 16 + ln] =
            (bf16_t)cacc[g][nt][r];
}

// ---------------------------------------------------------------------------
extern "C" void kernel_launch(void* const* d_in, const int* in_sizes, int n_in,
                              void* d_out, int out_size, void* d_ws, size_t ws_size,
                              hipStream_t stream) {
  const float* query = (const float*)d_in[0];
  const float* key_  = (const float*)d_in[1];
  const float* value = (const float*)d_in[2];
  const float* Wq = (const float*)d_in[3];
  const float* bq = (const float*)d_in[4];
  const float* Wk = (const float*)d_in[5];
  const float* bk = (const float*)d_in[6];
  const float* Wv = (const float*)d_in[7];
  const float* bv = (const float*)d_in[8];
  const float* hm = (const float*)d_in[9];
  const float* Wo = (const float*)d_in[10];
  const float* bo = (const float*)d_in[11];
  float* out = (float*)d_out;

  char* ws = (char*)d_ws;
  size_t off = 0;
  auto alloc = [&](size_t bytes) -> void* {
    void* p = ws + off;
    off += (bytes + 255) & ~(size_t)255;
    return p;
  };
  // ---- workspace ~34 MB ----
  float*  MIXW = (float*) alloc(256 * 4);
  float*  Zb   = (float*) alloc((size_t)B_ * H_ * S_ * 4);  // 256 KB
  bf16_t* Qp   = (bf16_t*)alloc((size_t)B_ * S_ * E_ * 2);  // 8.4 MB (scaled 1/8)
  bf16_t* Kp   = (bf16_t*)alloc((size_t)B_ * S_ * E_ * 2);  // 8.4 MB
  bf16_t* Vp   = (bf16_t*)alloc((size_t)B_ * S_ * E_ * 2);  // 8.4 MB
  bf16_t* Vtt  = (bf16_t*)alloc((size_t)B_ * S_ * E_ * 2);  // 8.4 MB [b,g,d,s]
  bf16_t* CTX  = Vp;  // alias: Vp dead after transpose_v (stream-ordered)
  (void)in_sizes; (void)n_in; (void)out_size; (void)ws_size;

  mix_kernel<<<1, 256, 0, stream>>>(hm, MIXW);

  GemmSec sq{query, bq, Wq, Qp, 0.125f};
  GemmSec sk{key_,  bk, Wk, Kp, 1.f};
  GemmSec sv{value, bv, Wv, Vp, 1.f};
  gemm_kernel<true, false><<<dim3(8, 32, 3), 256, 0, stream>>>(sq, sk, sv);

  transpose_v_kernel<<<dim3(64, 2, 32), 256, 0, stream>>>(Vp, Vtt);
  pass1_kernel<<<dim3(8, 32, 1), 256, 0, stream>>>(Qp, Kp, Zb);
  pass2_kernel<<<dim3(256, 1, 1), 256, 0, stream>>>(Qp, Kp, Vtt, Zb, MIXW, CTX);

  GemmSec so{CTX, bo, Wo, out, 1.f};
  gemm_kernel<false, true><<<dim3(8, 32, 1), 256, 0, stream>>>(so, so, so);
}